// Round 1
// baseline (1313.138 us; speedup 1.0000x reference)
//
#include <hip/hip_runtime.h>
#include <math.h>

#define BS 4096
#define FD 768
#define PD 500
#define ZD 300
#define RNUM 10

typedef short bf16x8 __attribute__((ext_vector_type(8)));
typedef float f32x4 __attribute__((ext_vector_type(4)));

__device__ __forceinline__ unsigned int fbits(float f) {
  union { float f; unsigned int u; } v; v.f = f; return v.u;
}

// pack two fp32 -> two bf16 (round-half-up) in one v_perm
__device__ __forceinline__ unsigned int pack2bf(float f0, float f1) {
  unsigned int u0 = fbits(f0) + 0x8000u;
  unsigned int u1 = fbits(f1) + 0x8000u;
  return __builtin_amdgcn_perm(u1, u0, 0x07060302u);
}

// ---------------------------------------------------------------------------
// fp32 tiled GEMM (kept for the small p2 layer): C = act(A@W^T + b)
// ---------------------------------------------------------------------------
#define BM 128
#define BN 64
#define BK 16
#define TM 8
#define TN 4
template <int ACT>
__global__ __launch_bounds__(256) void gemm_kernel(
    const float* __restrict__ A, const float* __restrict__ W,
    const float* __restrict__ bias, float* __restrict__ C,
    int M, int N, int K) {
  __shared__ float As[BK][BM + 4];
  __shared__ float Bs[BK][BN + 4];
  const int m0 = blockIdx.x * BM;
  const int n0 = blockIdx.y * BN;
  const int tid = threadIdx.x;
  const int tx = tid & 15;
  const int ty = tid >> 4;
  float acc[TM][TN];
#pragma unroll
  for (int i = 0; i < TM; i++)
#pragma unroll
    for (int j = 0; j < TN; j++) acc[i][j] = 0.f;
  const int l_row = tid >> 2;
  const int l_k4 = (tid & 3) * 4;
  for (int k0 = 0; k0 < K; k0 += BK) {
#pragma unroll
    for (int half = 0; half < 2; ++half) {
      int m = m0 + l_row + half * 64;
      int k = k0 + l_k4;
      float4 v = make_float4(0.f, 0.f, 0.f, 0.f);
      if (m < M && k + 4 <= K) v = *(const float4*)(A + (size_t)m * K + k);
      As[l_k4 + 0][l_row + half * 64] = v.x;
      As[l_k4 + 1][l_row + half * 64] = v.y;
      As[l_k4 + 2][l_row + half * 64] = v.z;
      As[l_k4 + 3][l_row + half * 64] = v.w;
    }
    {
      int n = n0 + l_row;
      int k = k0 + l_k4;
      float4 v = make_float4(0.f, 0.f, 0.f, 0.f);
      if (n < N && k + 4 <= K) v = *(const float4*)(W + (size_t)n * K + k);
      Bs[l_k4 + 0][l_row] = v.x;
      Bs[l_k4 + 1][l_row] = v.y;
      Bs[l_k4 + 2][l_row] = v.z;
      Bs[l_k4 + 3][l_row] = v.w;
    }
    __syncthreads();
#pragma unroll
    for (int k = 0; k < BK; k++) {
      float a[TM], b[TN];
#pragma unroll
      for (int i = 0; i < TM; i++) a[i] = As[k][ty * TM + i];
#pragma unroll
      for (int j = 0; j < TN; j++) b[j] = Bs[k][tx * TN + j];
#pragma unroll
      for (int i = 0; i < TM; i++)
#pragma unroll
        for (int j = 0; j < TN; j++) acc[i][j] += a[i] * b[j];
    }
    __syncthreads();
  }
#pragma unroll
  for (int i = 0; i < TM; i++) {
    int m = m0 + ty * TM + i;
    if (m >= M) continue;
#pragma unroll
    for (int j = 0; j < TN; j++) {
      int n = n0 + tx * TN + j;
      if (n >= N) continue;
      float v = acc[i][j] + bias[n];
      if (ACT == 1) v = fmaxf(v, 0.f);
      C[(size_t)m * N + n] = v;
    }
  }
}

// ---------------------------------------------------------------------------
// pad-cast fp32 weight [rs,cs] -> bf16 [rd,cd], zero padded
// ---------------------------------------------------------------------------
__global__ __launch_bounds__(256) void padcast(
    const float* __restrict__ src, unsigned short* __restrict__ dst,
    int rs, int cs, int rd, int cd) {
  int i = blockIdx.x * 256 + threadIdx.x;
  if (i >= rd * cd) return;
  int r = i / cd, c = i - r * cd;
  float v = (r < rs && c < cs) ? src[(size_t)r * cs + c] : 0.f;
  dst[i] = (unsigned short)((fbits(v) + 0x8000u) >> 16);
}

// ===========================================================================
// bf16 MFMA GEMM core (128x128 tile, 4 waves of 64x64, BK=32).
// NEW: double-buffered LDS + register prefetch + raw s_barrier with
// lgkmcnt(0)-only drain (one barrier per K-step; global loads for tile t+1
// stay in flight across the barrier and are consumed by the pack just before
// the ds_write of the t+1 buffer). Race argument: between consecutive
// barriers every wave reads buf[t&1] and writes only buf[(t&1)^1]; the
// lgkmcnt(0) before each barrier makes all prior DS ops visible.
// LDS swizzle: granule kq stored at slot (kq ^ ((row>>1)&3)) (verified,
// 0 bank conflicts measured).
// MFMA frag maps (verified): A/B lane holds row/col (lane&15), k=(lane>>4)*8+i
// C/D: col=lane&15, row=(lane>>4)*4+reg.
// ===========================================================================
template <int ACT>  // 0=none, 1=relu
__global__ __launch_bounds__(256) void mfma_gemm(
    const float* __restrict__ A, int lda, int Ka,
    const unsigned short* __restrict__ B, int Kp,
    const float* __restrict__ bias, float* __restrict__ C, int Nout) {
  __shared__ unsigned short ldsA[2][128 * 32];
  __shared__ unsigned short ldsB[2][128 * 32];
  const int tid = threadIdx.x;
  const int n0 = blockIdx.x * 128;
  const int m0 = blockIdx.y * 128;

  const int arow = tid >> 1;
  const int ahalf = (tid & 1) << 4;  // k offset 0/16
  const int ag = (tid & 1) << 1;     // granule 0/2
  const int aswz = (arow >> 1) & 3;
  const int aw0 = (arow * 4 + ((ag | 0) ^ aswz)) * 8;
  const int aw1 = (arow * 4 + ((ag | 1) ^ aswz)) * 8;
  const float* aptr = A + (size_t)(m0 + arow) * lda;
  const unsigned short* bptr = B + (size_t)(n0 + arow) * Kp + ahalf;

  const int lane = tid & 63;
  const int wave = tid >> 6;
  const int wm = (wave >> 1) << 6;
  const int wn = (wave & 1) << 6;
  const int r16 = lane & 15;
  const int kq = lane >> 4;

  int afoff[4], bfoff[4];
#pragma unroll
  for (int i = 0; i < 4; i++) {
    int rowA = wm + i * 16 + r16;
    afoff[i] = (rowA * 4 + (kq ^ ((rowA >> 1) & 3))) * 8;
    int rowB = wn + i * 16 + r16;
    bfoff[i] = (rowB * 4 + (kq ^ ((rowB >> 1) & 3))) * 8;
  }

  f32x4 acc[4][4] = {};
  const int NT = Kp >> 5;

  float4 f[4];
  uint4 bv0, bv1;
  // ---- prologue: stage K-tile 0 into buf 0 ----
#pragma unroll
  for (int q = 0; q < 4; q++) {
    int k = ahalf + q * 4;
    f[q] = (k < Ka) ? *(const float4*)(aptr + k) : make_float4(0.f, 0.f, 0.f, 0.f);
  }
  bv0 = *(const uint4*)(bptr + 0);
  bv1 = *(const uint4*)(bptr + 8);
  {
    uint4 w0, w1;
    w0.x = pack2bf(f[0].x, f[0].y); w0.y = pack2bf(f[0].z, f[0].w);
    w0.z = pack2bf(f[1].x, f[1].y); w0.w = pack2bf(f[1].z, f[1].w);
    w1.x = pack2bf(f[2].x, f[2].y); w1.y = pack2bf(f[2].z, f[2].w);
    w1.z = pack2bf(f[3].x, f[3].y); w1.w = pack2bf(f[3].z, f[3].w);
    *(uint4*)&ldsA[0][aw0] = w0;
    *(uint4*)&ldsA[0][aw1] = w1;
    *(uint4*)&ldsB[0][aw0] = bv0;
    *(uint4*)&ldsB[0][aw1] = bv1;
  }

#pragma unroll 2
  for (int t = 0; t < NT; ++t) {
    const int cb = t & 1;
    asm volatile("s_waitcnt lgkmcnt(0)" ::: "memory");
    __builtin_amdgcn_s_barrier();
    if (t + 1 < NT) {
      const int k0 = (t + 1) << 5;
#pragma unroll
      for (int q = 0; q < 4; q++) {
        int k = k0 + ahalf + q * 4;
        f[q] = (k < Ka) ? *(const float4*)(aptr + k)
                        : make_float4(0.f, 0.f, 0.f, 0.f);
      }
      bv0 = *(const uint4*)(bptr + k0);
      bv1 = *(const uint4*)(bptr + k0 + 8);
    }
    bf16x8 a[4], b[4];
#pragma unroll
    for (int i = 0; i < 4; i++) a[i] = *(const bf16x8*)&ldsA[cb][afoff[i]];
#pragma unroll
    for (int i = 0; i < 4; i++) b[i] = *(const bf16x8*)&ldsB[cb][bfoff[i]];
#pragma unroll
    for (int i = 0; i < 4; i++)
#pragma unroll
      for (int j = 0; j < 4; j++)
        acc[i][j] = __builtin_amdgcn_mfma_f32_16x16x32_bf16(a[i], b[j], acc[i][j], 0, 0, 0);
    if (t + 1 < NT) {
      uint4 w0, w1;
      w0.x = pack2bf(f[0].x, f[0].y); w0.y = pack2bf(f[0].z, f[0].w);
      w0.z = pack2bf(f[1].x, f[1].y); w0.w = pack2bf(f[1].z, f[1].w);
      w1.x = pack2bf(f[2].x, f[2].y); w1.y = pack2bf(f[2].z, f[2].w);
      w1.z = pack2bf(f[3].x, f[3].y); w1.w = pack2bf(f[3].z, f[3].w);
      *(uint4*)&ldsA[cb ^ 1][aw0] = w0;
      *(uint4*)&ldsA[cb ^ 1][aw1] = w1;
      *(uint4*)&ldsB[cb ^ 1][aw0] = bv0;
      *(uint4*)&ldsB[cb ^ 1][aw1] = bv1;
    }
  }

#pragma unroll
  for (int j = 0; j < 4; j++) {
    int n = n0 + wn + j * 16 + r16;
    if (n >= Nout) continue;
    float bi = bias[n];
#pragma unroll
    for (int i = 0; i < 4; i++) {
#pragma unroll
      for (int r = 0; r < 4; r++) {
        int m = m0 + wm + i * 16 + kq * 4 + r;
        float v = acc[i][j][r] + bi;
        if (ACT == 1) v = fmaxf(v, 0.f);
        C[(size_t)m * Nout + n] = v;
      }
    }
  }
}

// ===========================================================================
// Embedding MFMA GEMM, NEW STRUCTURE:
//  - 512 threads / block, tile 128M x 512N (FULL padded N in one block so A
//    is fetched from HBM exactly once; B is 786KB/group -> L2 resident).
//  - wave grid 2m x 4n; each wave 64x128 -> acc[4][8] f32x4 (128 VGPR).
//  - same dbuf + reg-prefetch + raw-barrier pipeline as mfma_gemm.
//  - epilogue: groups 0-2 plain tanh stores; groups 3-5 reduce the 10-row
//    retrieval batches in LDS (column chunks of 64), then ONE plain store per
//    interior batch and atomicAdd only for tile-boundary batches (~1M atomics
//    instead of 61M). E0 (batch-0 rt/rv rows) written from the LDS chunk.
// Row space: [0,4096) txt, [4096,8192) vis, [8192,12288) usr,
// [12288,53248) rt, [53248,94208) rv, [94208,135168) ru.
// ===========================================================================
struct EmbedArgs {
  const float* A[6];
  const float* bias[6];
};

__global__ __launch_bounds__(512, 2) void embed_mfma(
    EmbedArgs ea, const unsigned short* __restrict__ Wbf,
    float* __restrict__ S, float* __restrict__ E0) {
  __shared__ unsigned short ldsA[2][128 * 32];  // 16 KB
  __shared__ unsigned short ldsB[2][512 * 32];  // 64 KB
  const int tid = threadIdx.x;
  const int m0 = blockIdx.x * 128;

  int g, base;
  if (m0 < 4096) { g = 0; base = 0; }
  else if (m0 < 8192) { g = 1; base = 4096; }
  else if (m0 < 12288) { g = 2; base = 8192; }
  else if (m0 < 53248) { g = 3; base = 12288; }
  else if (m0 < 94208) { g = 4; base = 53248; }
  else { g = 5; base = 94208; }

  // A staging: row = tid>>2 (0..127), k-granule q = tid&3 (8 fp32 -> 8 bf16)
  const int arow = tid >> 2;
  const int aq = tid & 3;
  const int aswz = (arow >> 1) & 3;
  const int awoff = (arow * 4 + (aq ^ aswz)) * 8;
  const float* aptr = ea.A[g] + (size_t)(m0 - base + arow) * FD + aq * 8;

  // B staging: row = tid (0..511), all 4 granules (one 64B line per thread)
  const int brow = tid;
  const int bswz = (brow >> 1) & 3;
  int bwoff[4];
#pragma unroll
  for (int q = 0; q < 4; q++) bwoff[q] = (brow * 4 + (q ^ bswz)) * 8;
  const unsigned short* bptr = Wbf + (size_t)g * 512 * FD + (size_t)brow * FD;

  const int lane = tid & 63;
  const int wave = tid >> 6;
  const int wm = (wave >> 2) << 6;  // 0 / 64
  const int wn = (wave & 3) << 7;   // 0 / 128 / 256 / 384
  const int r16 = lane & 15;
  const int kq = lane >> 4;

  int afoff[4], bfoff[8];
#pragma unroll
  for (int i = 0; i < 4; i++) {
    int rowA = wm + i * 16 + r16;
    afoff[i] = (rowA * 4 + (kq ^ ((rowA >> 1) & 3))) * 8;
  }
#pragma unroll
  for (int j = 0; j < 8; j++) {
    int rowB = wn + j * 16 + r16;
    bfoff[j] = (rowB * 4 + (kq ^ ((rowB >> 1) & 3))) * 8;
  }

  f32x4 acc[4][8] = {};

  // ---- prologue: stage K-tile 0 into buf 0 ----
  float4 fa0 = *(const float4*)(aptr + 0);
  float4 fa1 = *(const float4*)(aptr + 4);
  uint4 bv[4];
#pragma unroll
  for (int q = 0; q < 4; q++) bv[q] = *(const uint4*)(bptr + q * 8);
  {
    uint4 aw;
    aw.x = pack2bf(fa0.x, fa0.y); aw.y = pack2bf(fa0.z, fa0.w);
    aw.z = pack2bf(fa1.x, fa1.y); aw.w = pack2bf(fa1.z, fa1.w);
    *(uint4*)&ldsA[0][awoff] = aw;
#pragma unroll
    for (int q = 0; q < 4; q++) *(uint4*)&ldsB[0][bwoff[q]] = bv[q];
  }

  const int NT = FD / 32;  // 24
#pragma unroll 2
  for (int t = 0; t < NT; ++t) {
    const int cb = t & 1;
    asm volatile("s_waitcnt lgkmcnt(0)" ::: "memory");
    __builtin_amdgcn_s_barrier();
    if (t + 1 < NT) {
      const float* ap = aptr + (t + 1) * 32;
      fa0 = *(const float4*)(ap + 0);
      fa1 = *(const float4*)(ap + 4);
      const unsigned short* bp = bptr + (t + 1) * 32;
#pragma unroll
      for (int q = 0; q < 4; q++) bv[q] = *(const uint4*)(bp + q * 8);
    }
    bf16x8 a[4], b[8];
#pragma unroll
    for (int i = 0; i < 4; i++) a[i] = *(const bf16x8*)&ldsA[cb][afoff[i]];
#pragma unroll
    for (int j = 0; j < 8; j++) b[j] = *(const bf16x8*)&ldsB[cb][bfoff[j]];
#pragma unroll
    for (int i = 0; i < 4; i++)
#pragma unroll
      for (int j = 0; j < 8; j++)
        acc[i][j] = __builtin_amdgcn_mfma_f32_16x16x32_bf16(a[i], b[j], acc[i][j], 0, 0, 0);
    if (t + 1 < NT) {
      uint4 aw;
      aw.x = pack2bf(fa0.x, fa0.y); aw.y = pack2bf(fa0.z, fa0.w);
      aw.z = pack2bf(fa1.x, fa1.y); aw.w = pack2bf(fa1.z, fa1.w);
      *(uint4*)&ldsA[cb ^ 1][awoff] = aw;
#pragma unroll
      for (int q = 0; q < 4; q++) *(uint4*)&ldsB[cb ^ 1][bwoff[q]] = bv[q];
    }
  }

  const float* bias = ea.bias[g];
  if (g < 3) {
#pragma unroll
    for (int j = 0; j < 8; j++) {
      int n = wn + j * 16 + r16;
      if (n >= PD) continue;
      float bi = bias[n];
#pragma unroll
      for (int i = 0; i < 4; i++) {
#pragma unroll
        for (int r = 0; r < 4; r++) {
          int rl = m0 - base + wm + i * 16 + kq * 4 + r;
          S[((size_t)g * BS + rl) * PD + n] = tanhf(acc[i][j][r] + bi);
        }
      }
    }
    return;
  }

  // ---- g >= 3: per-batch (10-row) reduction via LDS column chunks ----
  const int R0 = m0 - base;          // multiple of 128
  const int b0 = R0 / 10;
  const int b1 = (R0 + 127) / 10;
  const int ng = b1 - b0 + 1;        // 13 or 14
  float* red = (float*)&ldsB[0][0];  // [128][68] fp32 = 34.8 KB (LDS reuse)
  const int myc = wave & 3;
  __syncthreads();  // all frag reads of last K-tile done before LDS reuse
  for (int ch = 0; ch < 8; ++ch) {
    if ((ch >> 1) == myc) {
      // this wave's 2 m-halves write cols [ch*64, ch*64+64) (pre-tanh + bias)
#pragma unroll
      for (int jj = 0; jj < 4; jj++) {
        int j = ((ch & 1) << 2) + jj;
        int n = wn + j * 16 + r16;
        int cl = (jj << 4) + r16;  // local col 0..63
        float bi = (n < PD) ? bias[n] : 0.f;
#pragma unroll
        for (int i = 0; i < 4; i++) {
#pragma unroll
          for (int r = 0; r < 4; r++) {
            int row = wm + i * 16 + kq * 4 + r;
            red[row * 68 + cl] = acc[i][j][r] + bi;
          }
        }
      }
    }
    __syncthreads();
    for (int task = tid; task < ng * 64; task += 512) {
      int cl = task & 63;
      int bb = b0 + (task >> 6);
      int n = (ch << 6) + cl;
      if (n < PD) {
        int rlo = bb * 10 - R0;
        int rhi = rlo + 9;
        int lo = rlo < 0 ? 0 : rlo;
        int hi = rhi > 127 ? 127 : rhi;
        float s = 0.f;
        for (int r = lo; r <= hi; r++) s += tanhf(red[r * 68 + cl]);
        size_t idx = ((size_t)g * BS + bb) * PD + n;
        if (hi - lo == 9) S[idx] = s;       // batch fully inside this tile
        else atomicAdd(&S[idx], s);         // split across two tiles
        if (g != 5 && bb == 0 && R0 == 0) {
#pragma unroll
          for (int rr = 0; rr < 10; rr++)
            E0[((size_t)(g - 3) * 10 + rr) * PD + n] = tanhf(red[rr * 68 + cl]);
        }
      }
    }
    __syncthreads();
  }
}

// ---------------------------------------------------------------------------
// Edge means (fp32): Mn[b*4+e][k]
// ---------------------------------------------------------------------------
__global__ __launch_bounds__(256) void means_kernel(
    const float* __restrict__ S, float* __restrict__ Mn) {
  const int total = 4 * BS * PD;
  for (int i = blockIdx.x * blockDim.x + threadIdx.x; i < total;
       i += gridDim.x * blockDim.x) {
    int m = i / PD;
    int k = i - m * PD;
    int b = m >> 2, e = m & 3;
    float v;
    const size_t o = (size_t)b * PD + k;
    if (e == 0)
      v = (S[o] + S[(size_t)BS * PD + o] + S[2 * (size_t)BS * PD + o]) * (1.f / 3.f);
    else if (e == 1)
      v = (S[3 * (size_t)BS * PD + o] + S[o]) * (1.f / 11.f);
    else if (e == 2)
      v = (S[4 * (size_t)BS * PD + o] + S[(size_t)BS * PD + o]) * (1.f / 11.f);
    else
      v = (S[5 * (size_t)BS * PD + o] + S[2 * (size_t)BS * PD + o]) * (1.f / 11.f);
    Mn[i] = v;
  }
}

// ---------------------------------------------------------------------------
__global__ __launch_bounds__(256) void xte_kernel(
    const float* __restrict__ E0, const float* __restrict__ hg_w,
    const float* __restrict__ hg_b, float* __restrict__ XtE) {
  const int i = blockIdx.x;  // 0..19
  __shared__ float row[PD];
  for (int k = threadIdx.x; k < PD; k += 256) row[k] = E0[(size_t)i * PD + k];
  __syncthreads();
  for (int n = threadIdx.x; n < ZD; n += 256) {
    float s = 0.f;
    const float* w = hg_w + (size_t)n * PD;
    for (int k = 0; k < PD; k++) s += row[k] * w[k];
    XtE[(size_t)i * ZD + n] = s + hg_b[n];
  }
}

// ---------------------------------------------------------------------------
__global__ __launch_bounds__(256) void feat_kernel(
    const float* __restrict__ Y, const float* __restrict__ XtE,
    const float* __restrict__ sim_in, const float* __restrict__ label,
    const float* __restrict__ lbl_w, const float* __restrict__ lbl_b,
    float* __restrict__ feat) {
  const int b = blockIdx.x;
  __shared__ float w[RNUM];
  __shared__ float lbl_agg_s;
  if (threadIdx.x == 0) {
    float s[RNUM], mx = -1e30f;
    for (int r = 0; r < RNUM; r++) {
      s[r] = sim_in[(size_t)b * RNUM + r];
      mx = fmaxf(mx, s[r]);
    }
    float sum = 0.f;
    for (int r = 0; r < RNUM; r++) { s[r] = expf(s[r] - mx); sum += s[r]; }
    float la = 0.f;
    for (int r = 0; r < RNUM; r++) {
      w[r] = s[r] / sum;
      la += w[r] * label[(size_t)b * RNUM + r];
    }
    lbl_agg_s = la;
  }
  __syncthreads();
  const float* Yb = Y + (size_t)b * 4 * ZD;
  float* fb = feat + (size_t)b * 7 * ZD;
  const float la = lbl_agg_s;
  for (int n = threadIdx.x; n < ZD; n += blockDim.x) {
    float y0 = Yb[n], y1 = Yb[ZD + n], y2 = Yb[2 * ZD + n], y3 = Yb[3 * ZD + n];
    fb[n] = fmaxf(0.5f * (y0 + y1), 0.f);
    fb[ZD + n] = fmaxf(0.5f * (y0 + y2), 0.f);
    fb[2 * ZD + n] = fmaxf(0.5f * (y0 + y3), 0.f);
    float rv, rt;
    if (b == 0) {
      rv = 0.f; rt = 0.f;
      for (int r = 0; r < RNUM; r++) {
        float yp = 0.5f * (XtE[(size_t)r * ZD + n] + XtE[(size_t)(10 + r) * ZD + n]);
        rt += w[r] * fmaxf(0.5f * (y1 + yp), 0.f);
        rv += w[r] * fmaxf(0.5f * (y2 + yp), 0.f);
      }
    } else {
      rt = fmaxf(y1, 0.f);
      rv = fmaxf(y2, 0.f);
    }
    fb[3 * ZD + n] = rv;
    fb[4 * ZD + n] = rt;
    fb[5 * ZD + n] = fmaxf(y3, 0.f);
    fb[6 * ZD + n] = fmaxf(la * lbl_w[n] + lbl_b[n], 0.f);
  }
}

// ---------------------------------------------------------------------------
__global__ __launch_bounds__(256) void head_kernel(
    const float* __restrict__ h2, const float* __restrict__ p3_w,
    const float* __restrict__ p3_b, float* __restrict__ out) {
  const int wave = (blockIdx.x * blockDim.x + threadIdx.x) >> 6;
  const int lane = threadIdx.x & 63;
  if (wave >= BS) return;
  const float* row = h2 + (size_t)wave * 200;
  float s = 0.f;
  for (int k = lane; k < 200; k += 64) s += row[k] * p3_w[k];
#pragma unroll
  for (int off = 32; off; off >>= 1) s += __shfl_down(s, off, 64);
  if (lane == 0) out[wave] = 1.f / (1.f + expf(-(s + p3_b[0])));
}

// ---------------------------------------------------------------------------
extern "C" void kernel_launch(void* const* d_in, const int* in_sizes, int n_in,
                              void* d_out, int out_size, void* d_ws,
                              size_t ws_size, hipStream_t stream) {
  (void)in_sizes; (void)n_in; (void)out_size; (void)ws_size;

  const float* visual = (const float*)d_in[0];
  const float* textual = (const float*)d_in[1];
  const float* similarity = (const float*)d_in[2];
  const float* r_visual = (const float*)d_in[3];
  const float* r_textual = (const float*)d_in[4];
  const float* r_label = (const float*)d_in[5];
  const float* user = (const float*)d_in[6];
  const float* r_user = (const float*)d_in[7];
  const float* vis_w = (const float*)d_in[9];
  const float* vis_b = (const float*)d_in[10];
  const float* txt_w = (const float*)d_in[11];
  const float* txt_b = (const float*)d_in[12];
  const float* usr_w = (const float*)d_in[13];
  const float* usr_b = (const float*)d_in[14];
  const float* rvis_w = (const float*)d_in[15];
  const float* rvis_b = (const float*)d_in[16];
  const float* rtxt_w = (const float*)d_in[17];
  const float* rtxt_b = (const float*)d_in[18];
  const float* rusr_w = (const float*)d_in[19];
  const float* rusr_b = (const float*)d_in[20];
  const float* hg_w = (const float*)d_in[21];
  const float* hg_b = (const float*)d_in[22];
  const float* lbl_w = (const float*)d_in[23];
  const float* lbl_b = (const float*)d_in[24];
  const float* p1_w = (const float*)d_in[25];
  const float* p1_b = (const float*)d_in[26];
  const float* p2_w = (const float*)d_in[27];
  const float* p2_b = (const float*)d_in[28];
  const float* p3_w = (const float*)d_in[29];
  const float* p3_b = (const float*)d_in[30];
  float* out = (float*)d_out;

  // workspace layout
  float* ws = (float*)d_ws;
  float* S = ws;                            // 6*4096*500
  float* E0 = S + (size_t)6 * BS * PD;      // 20*500
  float* XtE = E0 + 20 * PD;                // 20*300
  float* Mn = XtE + 20 * ZD;                // 16384*500
  float* Y = Mn + (size_t)4 * BS * PD;      // 16384*300
  float* feat = Y + (size_t)4 * BS * ZD;    // 4096*2100
  float* h1 = feat + (size_t)BS * 7 * ZD;   // 4096*800
  float* h2 = h1 + (size_t)BS * 800;        // 4096*200
  unsigned short* Wbf = (unsigned short*)(h2 + (size_t)BS * 200);  // 6*512*768
  unsigned short* hgwbf = Wbf + (size_t)6 * 512 * FD;              // 384*512
  unsigned short* p1wbf = hgwbf + (size_t)384 * 512;               // 896*2112

  // pre-cast weights to zero-padded bf16
  const float* ew[6] = {txt_w, vis_w, usr_w, rtxt_w, rvis_w, rusr_w};
  for (int g = 0; g < 6; g++) {
    padcast<<<(512 * FD + 255) / 256, 256, 0, stream>>>(
        ew[g], Wbf + (size_t)g * 512 * FD, PD, FD, 512, FD);
  }
  padcast<<<(384 * 512 + 255) / 256, 256, 0, stream>>>(hg_w, hgwbf, ZD, PD, 384, 512);
  padcast<<<(896 * 2112 + 255) / 256, 256, 0, stream>>>(p1_w, p1wbf, 800, 2100, 896, 2112);

  // zero only the atomically-accumulated retrieval-group region of S
  hipMemsetAsync(S + (size_t)3 * BS * PD, 0, (size_t)3 * BS * PD * sizeof(float),
                 stream);

  EmbedArgs ea;
  ea.A[0] = textual;  ea.bias[0] = txt_b;
  ea.A[1] = visual;   ea.bias[1] = vis_b;
  ea.A[2] = user;     ea.bias[2] = usr_b;
  ea.A[3] = r_textual; ea.bias[3] = rtxt_b;
  ea.A[4] = r_visual;  ea.bias[4] = rvis_b;
  ea.A[5] = r_user;    ea.bias[5] = rusr_b;

  // one block per 128-row M-tile, full N=512 per block (A fetched once)
  embed_mfma<<<dim3(135168 / 128), 512, 0, stream>>>(ea, Wbf, S, E0);
  xte_kernel<<<20, 256, 0, stream>>>(E0, hg_w, hg_b, XtE);
  means_kernel<<<4096, 256, 0, stream>>>(S, Mn);
  mfma_gemm<0><<<dim3(3, 16384 / 128), 256, 0, stream>>>(
      Mn, PD, PD, hgwbf, 512, hg_b, Y, ZD);
  feat_kernel<<<BS, 256, 0, stream>>>(Y, XtE, similarity, r_label, lbl_w, lbl_b,
                                      feat);
  mfma_gemm<1><<<dim3(7, BS / 128), 256, 0, stream>>>(
      feat, 2100, 2100, p1wbf, 2112, p1_b, h1, 800);
  gemm_kernel<1><<<dim3(BS / BM, (200 + BN - 1) / BN), 256, 0, stream>>>(
      h1, p2_w, p2_b, h2, BS, 200, 800);
  head_kernel<<<BS * 64 / 256, 256, 0, stream>>>(h2, p3_w, p3_b, out);
}

// Round 2
// 1170.057 us; speedup vs baseline: 1.1223x; 1.1223x over previous
//
#include <hip/hip_runtime.h>
#include <math.h>

#define BS 4096
#define FD 768
#define PD 500
#define ZD 300
#define RNUM 10

typedef short bf16x8 __attribute__((ext_vector_type(8)));
typedef float f32x4 __attribute__((ext_vector_type(4)));

__device__ __forceinline__ unsigned int fbits(float f) {
  union { float f; unsigned int u; } v; v.f = f; return v.u;
}

// pack two fp32 -> two bf16 (round-half-up) in one v_perm
__device__ __forceinline__ unsigned int pack2bf(float f0, float f1) {
  unsigned int u0 = fbits(f0) + 0x8000u;
  unsigned int u1 = fbits(f1) + 0x8000u;
  return __builtin_amdgcn_perm(u1, u0, 0x07060302u);
}

// ---------------------------------------------------------------------------
// fp32 tiled GEMM (kept for the small p2 layer): C = act(A@W^T + b)
// ---------------------------------------------------------------------------
#define BM 128
#define BN 64
#define BK 16
#define TM 8
#define TN 4
template <int ACT>
__global__ __launch_bounds__(256) void gemm_kernel(
    const float* __restrict__ A, const float* __restrict__ W,
    const float* __restrict__ bias, float* __restrict__ C,
    int M, int N, int K) {
  __shared__ float As[BK][BM + 4];
  __shared__ float Bs[BK][BN + 4];
  const int m0 = blockIdx.x * BM;
  const int n0 = blockIdx.y * BN;
  const int tid = threadIdx.x;
  const int tx = tid & 15;
  const int ty = tid >> 4;
  float acc[TM][TN];
#pragma unroll
  for (int i = 0; i < TM; i++)
#pragma unroll
    for (int j = 0; j < TN; j++) acc[i][j] = 0.f;
  const int l_row = tid >> 2;
  const int l_k4 = (tid & 3) * 4;
  for (int k0 = 0; k0 < K; k0 += BK) {
#pragma unroll
    for (int half = 0; half < 2; ++half) {
      int m = m0 + l_row + half * 64;
      int k = k0 + l_k4;
      float4 v = make_float4(0.f, 0.f, 0.f, 0.f);
      if (m < M && k + 4 <= K) v = *(const float4*)(A + (size_t)m * K + k);
      As[l_k4 + 0][l_row + half * 64] = v.x;
      As[l_k4 + 1][l_row + half * 64] = v.y;
      As[l_k4 + 2][l_row + half * 64] = v.z;
      As[l_k4 + 3][l_row + half * 64] = v.w;
    }
    {
      int n = n0 + l_row;
      int k = k0 + l_k4;
      float4 v = make_float4(0.f, 0.f, 0.f, 0.f);
      if (n < N && k + 4 <= K) v = *(const float4*)(W + (size_t)n * K + k);
      Bs[l_k4 + 0][l_row] = v.x;
      Bs[l_k4 + 1][l_row] = v.y;
      Bs[l_k4 + 2][l_row] = v.z;
      Bs[l_k4 + 3][l_row] = v.w;
    }
    __syncthreads();
#pragma unroll
    for (int k = 0; k < BK; k++) {
      float a[TM], b[TN];
#pragma unroll
      for (int i = 0; i < TM; i++) a[i] = As[k][ty * TM + i];
#pragma unroll
      for (int j = 0; j < TN; j++) b[j] = Bs[k][tx * TN + j];
#pragma unroll
      for (int i = 0; i < TM; i++)
#pragma unroll
        for (int j = 0; j < TN; j++) acc[i][j] += a[i] * b[j];
    }
    __syncthreads();
  }
#pragma unroll
  for (int i = 0; i < TM; i++) {
    int m = m0 + ty * TM + i;
    if (m >= M) continue;
#pragma unroll
    for (int j = 0; j < TN; j++) {
      int n = n0 + tx * TN + j;
      if (n >= N) continue;
      float v = acc[i][j] + bias[n];
      if (ACT == 1) v = fmaxf(v, 0.f);
      C[(size_t)m * N + n] = v;
    }
  }
}

// ---------------------------------------------------------------------------
// pad-cast fp32 weight [rs,cs] -> bf16 [rd,cd], zero padded
// ---------------------------------------------------------------------------
__global__ __launch_bounds__(256) void padcast(
    const float* __restrict__ src, unsigned short* __restrict__ dst,
    int rs, int cs, int rd, int cd) {
  int i = blockIdx.x * 256 + threadIdx.x;
  if (i >= rd * cd) return;
  int r = i / cd, c = i - r * cd;
  float v = (r < rs && c < cs) ? src[(size_t)r * cs + c] : 0.f;
  dst[i] = (unsigned short)((fbits(v) + 0x8000u) >> 16);
}

// ===========================================================================
// bf16 MFMA GEMM core (128x128 tile, 4 waves of 64x64, BK=32).
// Double-buffered LDS + register prefetch + raw s_barrier with
// lgkmcnt(0)-only drain (one barrier per K-step; global loads for tile t+1
// stay in flight across the barrier). Race argument: between consecutive
// barriers every wave reads buf[t&1] and writes only buf[(t&1)^1]; the
// lgkmcnt(0) before each barrier makes all prior DS ops visible.
// LDS swizzle: granule kq stored at slot (kq ^ ((row>>1)&3)).
// MFMA frag maps (verified): A/B lane holds row/col (lane&15), k=(lane>>4)*8+i
// C/D: col=lane&15, row=(lane>>4)*4+reg.
// ===========================================================================
template <int ACT>  // 0=none, 1=relu
__global__ __launch_bounds__(256) void mfma_gemm(
    const float* __restrict__ A, int lda, int Ka,
    const unsigned short* __restrict__ B, int Kp,
    const float* __restrict__ bias, float* __restrict__ C, int Nout) {
  __shared__ unsigned short ldsA[2][128 * 32];
  __shared__ unsigned short ldsB[2][128 * 32];
  const int tid = threadIdx.x;
  const int n0 = blockIdx.x * 128;
  const int m0 = blockIdx.y * 128;

  const int arow = tid >> 1;
  const int ahalf = (tid & 1) << 4;  // k offset 0/16
  const int ag = (tid & 1) << 1;     // granule 0/2
  const int aswz = (arow >> 1) & 3;
  const int aw0 = (arow * 4 + ((ag | 0) ^ aswz)) * 8;
  const int aw1 = (arow * 4 + ((ag | 1) ^ aswz)) * 8;
  const float* aptr = A + (size_t)(m0 + arow) * lda;
  const unsigned short* bptr = B + (size_t)(n0 + arow) * Kp + ahalf;

  const int lane = tid & 63;
  const int wave = tid >> 6;
  const int wm = (wave >> 1) << 6;
  const int wn = (wave & 1) << 6;
  const int r16 = lane & 15;
  const int kq = lane >> 4;

  int afoff[4], bfoff[4];
#pragma unroll
  for (int i = 0; i < 4; i++) {
    int rowA = wm + i * 16 + r16;
    afoff[i] = (rowA * 4 + (kq ^ ((rowA >> 1) & 3))) * 8;
    int rowB = wn + i * 16 + r16;
    bfoff[i] = (rowB * 4 + (kq ^ ((rowB >> 1) & 3))) * 8;
  }

  f32x4 acc[4][4] = {};
  const int NT = Kp >> 5;

  float4 f[4];
  uint4 bv0, bv1;
  // ---- prologue: stage K-tile 0 into buf 0 ----
#pragma unroll
  for (int q = 0; q < 4; q++) {
    int k = ahalf + q * 4;
    f[q] = (k < Ka) ? *(const float4*)(aptr + k) : make_float4(0.f, 0.f, 0.f, 0.f);
  }
  bv0 = *(const uint4*)(bptr + 0);
  bv1 = *(const uint4*)(bptr + 8);
  {
    uint4 w0, w1;
    w0.x = pack2bf(f[0].x, f[0].y); w0.y = pack2bf(f[0].z, f[0].w);
    w0.z = pack2bf(f[1].x, f[1].y); w0.w = pack2bf(f[1].z, f[1].w);
    w1.x = pack2bf(f[2].x, f[2].y); w1.y = pack2bf(f[2].z, f[2].w);
    w1.z = pack2bf(f[3].x, f[3].y); w1.w = pack2bf(f[3].z, f[3].w);
    *(uint4*)&ldsA[0][aw0] = w0;
    *(uint4*)&ldsA[0][aw1] = w1;
    *(uint4*)&ldsB[0][aw0] = bv0;
    *(uint4*)&ldsB[0][aw1] = bv1;
  }

#pragma unroll 2
  for (int t = 0; t < NT; ++t) {
    const int cb = t & 1;
    asm volatile("s_waitcnt lgkmcnt(0)" ::: "memory");
    __builtin_amdgcn_s_barrier();
    if (t + 1 < NT) {
      const int k0 = (t + 1) << 5;
#pragma unroll
      for (int q = 0; q < 4; q++) {
        int k = k0 + ahalf + q * 4;
        f[q] = (k < Ka) ? *(const float4*)(aptr + k)
                        : make_float4(0.f, 0.f, 0.f, 0.f);
      }
      bv0 = *(const uint4*)(bptr + k0);
      bv1 = *(const uint4*)(bptr + k0 + 8);
    }
    bf16x8 a[4], b[4];
#pragma unroll
    for (int i = 0; i < 4; i++) a[i] = *(const bf16x8*)&ldsA[cb][afoff[i]];
#pragma unroll
    for (int i = 0; i < 4; i++) b[i] = *(const bf16x8*)&ldsB[cb][bfoff[i]];
#pragma unroll
    for (int i = 0; i < 4; i++)
#pragma unroll
      for (int j = 0; j < 4; j++)
        acc[i][j] = __builtin_amdgcn_mfma_f32_16x16x32_bf16(a[i], b[j], acc[i][j], 0, 0, 0);
    if (t + 1 < NT) {
      uint4 w0, w1;
      w0.x = pack2bf(f[0].x, f[0].y); w0.y = pack2bf(f[0].z, f[0].w);
      w0.z = pack2bf(f[1].x, f[1].y); w0.w = pack2bf(f[1].z, f[1].w);
      w1.x = pack2bf(f[2].x, f[2].y); w1.y = pack2bf(f[2].z, f[2].w);
      w1.z = pack2bf(f[3].x, f[3].y); w1.w = pack2bf(f[3].z, f[3].w);
      *(uint4*)&ldsA[cb ^ 1][aw0] = w0;
      *(uint4*)&ldsA[cb ^ 1][aw1] = w1;
      *(uint4*)&ldsB[cb ^ 1][aw0] = bv0;
      *(uint4*)&ldsB[cb ^ 1][aw1] = bv1;
    }
  }

#pragma unroll
  for (int j = 0; j < 4; j++) {
    int n = n0 + wn + j * 16 + r16;
    if (n >= Nout) continue;
    float bi = bias[n];
#pragma unroll
    for (int i = 0; i < 4; i++) {
#pragma unroll
      for (int r = 0; r < 4; r++) {
        int m = m0 + wm + i * 16 + kq * 4 + r;
        float v = acc[i][j][r] + bi;
        if (ACT == 1) v = fmaxf(v, 0.f);
        C[(size_t)m * Nout + n] = v;
      }
    }
  }
}

// ===========================================================================
// Embedding MFMA GEMM:
//  - 512 threads / block, tile 128M x 512N (FULL padded N in one block so A
//    is fetched from HBM exactly once; B is 786KB/group -> L2 resident).
//  - wave grid 2m x 4n; each wave 64x128 -> acc[4][8] f32x4 (128 VGPR).
//  - dbuf + reg-prefetch + raw-barrier pipeline as in mfma_gemm.
//  - epilogue: groups 0-2 plain tanh stores; groups 3-5 reduce the 10-row
//    retrieval batches in LDS (column chunks of 64). The chunk loop is
//    FULLY UNROLLED so every acc[][] index is compile-time constant —
//    rule #20: a single runtime index demotes the whole acc array to
//    scratch (R1: VGPR=104, +500MB scratch write traffic, MfmaUtil 5%).
// Row space: [0,4096) txt, [4096,8192) vis, [8192,12288) usr,
// [12288,53248) rt, [53248,94208) rv, [94208,135168) ru.
// ===========================================================================
struct EmbedArgs {
  const float* A[6];
  const float* bias[6];
};

__global__ __launch_bounds__(512, 2) void embed_mfma(
    EmbedArgs ea, const unsigned short* __restrict__ Wbf,
    float* __restrict__ S, float* __restrict__ E0) {
  __shared__ unsigned short ldsA[2][128 * 32];  // 16 KB
  __shared__ unsigned short ldsB[2][512 * 32];  // 64 KB
  const int tid = threadIdx.x;
  const int m0 = blockIdx.x * 128;

  int g, base;
  if (m0 < 4096) { g = 0; base = 0; }
  else if (m0 < 8192) { g = 1; base = 4096; }
  else if (m0 < 12288) { g = 2; base = 8192; }
  else if (m0 < 53248) { g = 3; base = 12288; }
  else if (m0 < 94208) { g = 4; base = 53248; }
  else { g = 5; base = 94208; }

  // A staging: row = tid>>2 (0..127), k-granule q = tid&3 (8 fp32 -> 8 bf16)
  const int arow = tid >> 2;
  const int aq = tid & 3;
  const int aswz = (arow >> 1) & 3;
  const int awoff = (arow * 4 + (aq ^ aswz)) * 8;
  const float* aptr = ea.A[g] + (size_t)(m0 - base + arow) * FD + aq * 8;

  // B staging: row = tid (0..511), all 4 granules (one 64B line per thread)
  const int brow = tid;
  const int bswz = (brow >> 1) & 3;
  int bwoff[4];
#pragma unroll
  for (int q = 0; q < 4; q++) bwoff[q] = (brow * 4 + (q ^ bswz)) * 8;
  const unsigned short* bptr = Wbf + (size_t)g * 512 * FD + (size_t)brow * FD;

  const int lane = tid & 63;
  const int wave = tid >> 6;
  const int wm = (wave >> 2) << 6;  // 0 / 64
  const int wn = (wave & 3) << 7;   // 0 / 128 / 256 / 384
  const int r16 = lane & 15;
  const int kq = lane >> 4;

  int afoff[4], bfoff[8];
#pragma unroll
  for (int i = 0; i < 4; i++) {
    int rowA = wm + i * 16 + r16;
    afoff[i] = (rowA * 4 + (kq ^ ((rowA >> 1) & 3))) * 8;
  }
#pragma unroll
  for (int j = 0; j < 8; j++) {
    int rowB = wn + j * 16 + r16;
    bfoff[j] = (rowB * 4 + (kq ^ ((rowB >> 1) & 3))) * 8;
  }

  f32x4 acc[4][8] = {};

  // ---- prologue: stage K-tile 0 into buf 0 ----
  float4 fa0 = *(const float4*)(aptr + 0);
  float4 fa1 = *(const float4*)(aptr + 4);
  uint4 bv[4];
#pragma unroll
  for (int q = 0; q < 4; q++) bv[q] = *(const uint4*)(bptr + q * 8);
  {
    uint4 aw;
    aw.x = pack2bf(fa0.x, fa0.y); aw.y = pack2bf(fa0.z, fa0.w);
    aw.z = pack2bf(fa1.x, fa1.y); aw.w = pack2bf(fa1.z, fa1.w);
    *(uint4*)&ldsA[0][awoff] = aw;
#pragma unroll
    for (int q = 0; q < 4; q++) *(uint4*)&ldsB[0][bwoff[q]] = bv[q];
  }

  const int NT = FD / 32;  // 24
#pragma unroll 2
  for (int t = 0; t < NT; ++t) {
    const int cb = t & 1;
    asm volatile("s_waitcnt lgkmcnt(0)" ::: "memory");
    __builtin_amdgcn_s_barrier();
    if (t + 1 < NT) {
      const float* ap = aptr + (t + 1) * 32;
      fa0 = *(const float4*)(ap + 0);
      fa1 = *(const float4*)(ap + 4);
      const unsigned short* bp = bptr + (t + 1) * 32;
#pragma unroll
      for (int q = 0; q < 4; q++) bv[q] = *(const uint4*)(bp + q * 8);
    }
    bf16x8 a[4], b[8];
#pragma unroll
    for (int i = 0; i < 4; i++) a[i] = *(const bf16x8*)&ldsA[cb][afoff[i]];
#pragma unroll
    for (int j = 0; j < 8; j++) b[j] = *(const bf16x8*)&ldsB[cb][bfoff[j]];
#pragma unroll
    for (int i = 0; i < 4; i++)
#pragma unroll
      for (int j = 0; j < 8; j++)
        acc[i][j] = __builtin_amdgcn_mfma_f32_16x16x32_bf16(a[i], b[j], acc[i][j], 0, 0, 0);
    if (t + 1 < NT) {
      uint4 aw;
      aw.x = pack2bf(fa0.x, fa0.y); aw.y = pack2bf(fa0.z, fa0.w);
      aw.z = pack2bf(fa1.x, fa1.y); aw.w = pack2bf(fa1.z, fa1.w);
      *(uint4*)&ldsA[cb ^ 1][awoff] = aw;
#pragma unroll
      for (int q = 0; q < 4; q++) *(uint4*)&ldsB[cb ^ 1][bwoff[q]] = bv[q];
    }
  }

  const float* bias = ea.bias[g];
  if (g < 3) {
#pragma unroll
    for (int j = 0; j < 8; j++) {
      int n = wn + j * 16 + r16;
      if (n >= PD) continue;
      float bi = bias[n];
#pragma unroll
      for (int i = 0; i < 4; i++) {
#pragma unroll
        for (int r = 0; r < 4; r++) {
          int rl = m0 - base + wm + i * 16 + kq * 4 + r;
          S[((size_t)g * BS + rl) * PD + n] = tanhf(acc[i][j][r] + bi);
        }
      }
    }
    return;
  }

  // ---- g >= 3: per-batch (10-row) reduction via LDS column chunks ----
  const int R0 = m0 - base;          // multiple of 128
  const int b0 = R0 / 10;
  const int b1 = (R0 + 127) / 10;
  const int ng = b1 - b0 + 1;        // 13 or 14
  float* red = (float*)&ldsB[0][0];  // [128][68] fp32 = 34.8 KB (LDS reuse)
  const int myc = wave & 3;
  __syncthreads();  // all frag reads of last K-tile done before LDS reuse
#pragma unroll
  for (int ch = 0; ch < 8; ++ch) {   // FULLY UNROLLED: acc indices static
    if ((ch >> 1) == myc) {
      // this wave's 2 m-halves write cols [ch*64, ch*64+64) (pre-tanh + bias)
#pragma unroll
      for (int jj = 0; jj < 4; jj++) {
        int j = ((ch & 1) << 2) + jj;
        int n = wn + j * 16 + r16;
        int cl = (jj << 4) + r16;  // local col 0..63
        float bi = (n < PD) ? bias[n] : 0.f;
#pragma unroll
        for (int i = 0; i < 4; i++) {
#pragma unroll
          for (int r = 0; r < 4; r++) {
            int row = wm + i * 16 + kq * 4 + r;
            red[row * 68 + cl] = acc[i][j][r] + bi;
          }
        }
      }
    }
    __syncthreads();
    for (int task = tid; task < ng * 64; task += 512) {
      int cl = task & 63;
      int bb = b0 + (task >> 6);
      int n = (ch << 6) + cl;
      if (n < PD) {
        int rlo = bb * 10 - R0;
        int rhi = rlo + 9;
        int lo = rlo < 0 ? 0 : rlo;
        int hi = rhi > 127 ? 127 : rhi;
        float s = 0.f;
        for (int r = lo; r <= hi; r++) s += tanhf(red[r * 68 + cl]);
        size_t idx = ((size_t)g * BS + bb) * PD + n;
        if (hi - lo == 9) S[idx] = s;       // batch fully inside this tile
        else atomicAdd(&S[idx], s);         // split across two tiles
        if (g != 5 && bb == 0 && R0 == 0) {
#pragma unroll
          for (int rr = 0; rr < 10; rr++)
            E0[((size_t)(g - 3) * 10 + rr) * PD + n] = tanhf(red[rr * 68 + cl]);
        }
      }
    }
    __syncthreads();
  }
}

// ---------------------------------------------------------------------------
// Edge means (fp32): Mn[b*4+e][k]
// ---------------------------------------------------------------------------
__global__ __launch_bounds__(256) void means_kernel(
    const float* __restrict__ S, float* __restrict__ Mn) {
  const int total = 4 * BS * PD;
  for (int i = blockIdx.x * blockDim.x + threadIdx.x; i < total;
       i += gridDim.x * blockDim.x) {
    int m = i / PD;
    int k = i - m * PD;
    int b = m >> 2, e = m & 3;
    float v;
    const size_t o = (size_t)b * PD + k;
    if (e == 0)
      v = (S[o] + S[(size_t)BS * PD + o] + S[2 * (size_t)BS * PD + o]) * (1.f / 3.f);
    else if (e == 1)
      v = (S[3 * (size_t)BS * PD + o] + S[o]) * (1.f / 11.f);
    else if (e == 2)
      v = (S[4 * (size_t)BS * PD + o] + S[(size_t)BS * PD + o]) * (1.f / 11.f);
    else
      v = (S[5 * (size_t)BS * PD + o] + S[2 * (size_t)BS * PD + o]) * (1.f / 11.f);
    Mn[i] = v;
  }
}

// ---------------------------------------------------------------------------
__global__ __launch_bounds__(256) void xte_kernel(
    const float* __restrict__ E0, const float* __restrict__ hg_w,
    const float* __restrict__ hg_b, float* __restrict__ XtE) {
  const int i = blockIdx.x;  // 0..19
  __shared__ float row[PD];
  for (int k = threadIdx.x; k < PD; k += 256) row[k] = E0[(size_t)i * PD + k];
  __syncthreads();
  for (int n = threadIdx.x; n < ZD; n += 256) {
    float s = 0.f;
    const float* w = hg_w + (size_t)n * PD;
    for (int k = 0; k < PD; k++) s += row[k] * w[k];
    XtE[(size_t)i * ZD + n] = s + hg_b[n];
  }
}

// ---------------------------------------------------------------------------
__global__ __launch_bounds__(256) void feat_kernel(
    const float* __restrict__ Y, const float* __restrict__ XtE,
    const float* __restrict__ sim_in, const float* __restrict__ label,
    const float* __restrict__ lbl_w, const float* __restrict__ lbl_b,
    float* __restrict__ feat) {
  const int b = blockIdx.x;
  __shared__ float w[RNUM];
  __shared__ float lbl_agg_s;
  if (threadIdx.x == 0) {
    float s[RNUM], mx = -1e30f;
    for (int r = 0; r < RNUM; r++) {
      s[r] = sim_in[(size_t)b * RNUM + r];
      mx = fmaxf(mx, s[r]);
    }
    float sum = 0.f;
    for (int r = 0; r < RNUM; r++) { s[r] = expf(s[r] - mx); sum += s[r]; }
    float la = 0.f;
    for (int r = 0; r < RNUM; r++) {
      w[r] = s[r] / sum;
      la += w[r] * label[(size_t)b * RNUM + r];
    }
    lbl_agg_s = la;
  }
  __syncthreads();
  const float* Yb = Y + (size_t)b * 4 * ZD;
  float* fb = feat + (size_t)b * 7 * ZD;
  const float la = lbl_agg_s;
  for (int n = threadIdx.x; n < ZD; n += blockDim.x) {
    float y0 = Yb[n], y1 = Yb[ZD + n], y2 = Yb[2 * ZD + n], y3 = Yb[3 * ZD + n];
    fb[n] = fmaxf(0.5f * (y0 + y1), 0.f);
    fb[ZD + n] = fmaxf(0.5f * (y0 + y2), 0.f);
    fb[2 * ZD + n] = fmaxf(0.5f * (y0 + y3), 0.f);
    float rv, rt;
    if (b == 0) {
      rv = 0.f; rt = 0.f;
      for (int r = 0; r < RNUM; r++) {
        float yp = 0.5f * (XtE[(size_t)r * ZD + n] + XtE[(size_t)(10 + r) * ZD + n]);
        rt += w[r] * fmaxf(0.5f * (y1 + yp), 0.f);
        rv += w[r] * fmaxf(0.5f * (y2 + yp), 0.f);
      }
    } else {
      rt = fmaxf(y1, 0.f);
      rv = fmaxf(y2, 0.f);
    }
    fb[3 * ZD + n] = rv;
    fb[4 * ZD + n] = rt;
    fb[5 * ZD + n] = fmaxf(y3, 0.f);
    fb[6 * ZD + n] = fmaxf(la * lbl_w[n] + lbl_b[n], 0.f);
  }
}

// ---------------------------------------------------------------------------
__global__ __launch_bounds__(256) void head_kernel(
    const float* __restrict__ h2, const float* __restrict__ p3_w,
    const float* __restrict__ p3_b, float* __restrict__ out) {
  const int wave = (blockIdx.x * blockDim.x + threadIdx.x) >> 6;
  const int lane = threadIdx.x & 63;
  if (wave >= BS) return;
  const float* row = h2 + (size_t)wave * 200;
  float s = 0.f;
  for (int k = lane; k < 200; k += 64) s += row[k] * p3_w[k];
#pragma unroll
  for (int off = 32; off; off >>= 1) s += __shfl_down(s, off, 64);
  if (lane == 0) out[wave] = 1.f / (1.f + expf(-(s + p3_b[0])));
}

// ---------------------------------------------------------------------------
extern "C" void kernel_launch(void* const* d_in, const int* in_sizes, int n_in,
                              void* d_out, int out_size, void* d_ws,
                              size_t ws_size, hipStream_t stream) {
  (void)in_sizes; (void)n_in; (void)out_size; (void)ws_size;

  const float* visual = (const float*)d_in[0];
  const float* textual = (const float*)d_in[1];
  const float* similarity = (const float*)d_in[2];
  const float* r_visual = (const float*)d_in[3];
  const float* r_textual = (const float*)d_in[4];
  const float* r_label = (const float*)d_in[5];
  const float* user = (const float*)d_in[6];
  const float* r_user = (const float*)d_in[7];
  const float* vis_w = (const float*)d_in[9];
  const float* vis_b = (const float*)d_in[10];
  const float* txt_w = (const float*)d_in[11];
  const float* txt_b = (const float*)d_in[12];
  const float* usr_w = (const float*)d_in[13];
  const float* usr_b = (const float*)d_in[14];
  const float* rvis_w = (const float*)d_in[15];
  const float* rvis_b = (const float*)d_in[16];
  const float* rtxt_w = (const float*)d_in[17];
  const float* rtxt_b = (const float*)d_in[18];
  const float* rusr_w = (const float*)d_in[19];
  const float* rusr_b = (const float*)d_in[20];
  const float* hg_w = (const float*)d_in[21];
  const float* hg_b = (const float*)d_in[22];
  const float* lbl_w = (const float*)d_in[23];
  const float* lbl_b = (const float*)d_in[24];
  const float* p1_w = (const float*)d_in[25];
  const float* p1_b = (const float*)d_in[26];
  const float* p2_w = (const float*)d_in[27];
  const float* p2_b = (const float*)d_in[28];
  const float* p3_w = (const float*)d_in[29];
  const float* p3_b = (const float*)d_in[30];
  float* out = (float*)d_out;

  // workspace layout
  float* ws = (float*)d_ws;
  float* S = ws;                            // 6*4096*500
  float* E0 = S + (size_t)6 * BS * PD;      // 20*500
  float* XtE = E0 + 20 * PD;                // 20*300
  float* Mn = XtE + 20 * ZD;                // 16384*500
  float* Y = Mn + (size_t)4 * BS * PD;      // 16384*300
  float* feat = Y + (size_t)4 * BS * ZD;    // 4096*2100
  float* h1 = feat + (size_t)BS * 7 * ZD;   // 4096*800
  float* h2 = h1 + (size_t)BS * 800;        // 4096*200
  unsigned short* Wbf = (unsigned short*)(h2 + (size_t)BS * 200);  // 6*512*768
  unsigned short* hgwbf = Wbf + (size_t)6 * 512 * FD;              // 384*512
  unsigned short* p1wbf = hgwbf + (size_t)384 * 512;               // 896*2112

  // pre-cast weights to zero-padded bf16
  const float* ew[6] = {txt_w, vis_w, usr_w, rtxt_w, rvis_w, rusr_w};
  for (int g = 0; g < 6; g++) {
    padcast<<<(512 * FD + 255) / 256, 256, 0, stream>>>(
        ew[g], Wbf + (size_t)g * 512 * FD, PD, FD, 512, FD);
  }
  padcast<<<(384 * 512 + 255) / 256, 256, 0, stream>>>(hg_w, hgwbf, ZD, PD, 384, 512);
  padcast<<<(896 * 2112 + 255) / 256, 256, 0, stream>>>(p1_w, p1wbf, 800, 2100, 896, 2112);

  // zero only the atomically-accumulated retrieval-group region of S
  hipMemsetAsync(S + (size_t)3 * BS * PD, 0, (size_t)3 * BS * PD * sizeof(float),
                 stream);

  EmbedArgs ea;
  ea.A[0] = textual;  ea.bias[0] = txt_b;
  ea.A[1] = visual;   ea.bias[1] = vis_b;
  ea.A[2] = user;     ea.bias[2] = usr_b;
  ea.A[3] = r_textual; ea.bias[3] = rtxt_b;
  ea.A[4] = r_visual;  ea.bias[4] = rvis_b;
  ea.A[5] = r_user;    ea.bias[5] = rusr_b;

  // one block per 128-row M-tile, full N=512 per block (A fetched once)
  embed_mfma<<<dim3(135168 / 128), 512, 0, stream>>>(ea, Wbf, S, E0);
  xte_kernel<<<20, 256, 0, stream>>>(E0, hg_w, hg_b, XtE);
  means_kernel<<<4096, 256, 0, stream>>>(S, Mn);
  mfma_gemm<0><<<dim3(3, 16384 / 128), 256, 0, stream>>>(
      Mn, PD, PD, hgwbf, 512, hg_b, Y, ZD);
  feat_kernel<<<BS, 256, 0, stream>>>(Y, XtE, similarity, r_label, lbl_w, lbl_b,
                                      feat);
  mfma_gemm<1><<<dim3(7, BS / 128), 256, 0, stream>>>(
      feat, 2100, 2100, p1wbf, 2112, p1_b, h1, 800);
  gemm_kernel<1><<<dim3(BS / BM, (200 + BN - 1) / BN), 256, 0, stream>>>(
      h1, p2_w, p2_b, h2, BS, 200, 800);
  head_kernel<<<BS * 64 / 256, 256, 0, stream>>>(h2, p3_w, p3_b, out);
}

// Round 3
// 1074.575 us; speedup vs baseline: 1.2220x; 1.0889x over previous
//
#include <hip/hip_runtime.h>
#include <math.h>

#define BS 4096
#define FD 768
#define PD 500
#define ZD 300
#define RNUM 10
#define SD 512  // padded row stride of S (64-B aligned stores)

typedef short bf16x8 __attribute__((ext_vector_type(8)));
typedef float f32x4 __attribute__((ext_vector_type(4)));

__device__ __forceinline__ unsigned int fbits(float f) {
  union { float f; unsigned int u; } v; v.f = f; return v.u;
}

// pack two fp32 -> two bf16 (round-half-up) in one v_perm
__device__ __forceinline__ unsigned int pack2bf(float f0, float f1) {
  unsigned int u0 = fbits(f0) + 0x8000u;
  unsigned int u1 = fbits(f1) + 0x8000u;
  return __builtin_amdgcn_perm(u1, u0, 0x07060302u);
}

// ---------------------------------------------------------------------------
// fp32 tiled GEMM (kept for the small p2 layer): C = act(A@W^T + b)
// ---------------------------------------------------------------------------
#define BM 128
#define BN 64
#define BK 16
#define TM 8
#define TN 4
template <int ACT>
__global__ __launch_bounds__(256) void gemm_kernel(
    const float* __restrict__ A, const float* __restrict__ W,
    const float* __restrict__ bias, float* __restrict__ C,
    int M, int N, int K) {
  __shared__ float As[BK][BM + 4];
  __shared__ float Bs[BK][BN + 4];
  const int m0 = blockIdx.x * BM;
  const int n0 = blockIdx.y * BN;
  const int tid = threadIdx.x;
  const int tx = tid & 15;
  const int ty = tid >> 4;
  float acc[TM][TN];
#pragma unroll
  for (int i = 0; i < TM; i++)
#pragma unroll
    for (int j = 0; j < TN; j++) acc[i][j] = 0.f;
  const int l_row = tid >> 2;
  const int l_k4 = (tid & 3) * 4;
  for (int k0 = 0; k0 < K; k0 += BK) {
#pragma unroll
    for (int half = 0; half < 2; ++half) {
      int m = m0 + l_row + half * 64;
      int k = k0 + l_k4;
      float4 v = make_float4(0.f, 0.f, 0.f, 0.f);
      if (m < M && k + 4 <= K) v = *(const float4*)(A + (size_t)m * K + k);
      As[l_k4 + 0][l_row + half * 64] = v.x;
      As[l_k4 + 1][l_row + half * 64] = v.y;
      As[l_k4 + 2][l_row + half * 64] = v.z;
      As[l_k4 + 3][l_row + half * 64] = v.w;
    }
    {
      int n = n0 + l_row;
      int k = k0 + l_k4;
      float4 v = make_float4(0.f, 0.f, 0.f, 0.f);
      if (n < N && k + 4 <= K) v = *(const float4*)(W + (size_t)n * K + k);
      Bs[l_k4 + 0][l_row] = v.x;
      Bs[l_k4 + 1][l_row] = v.y;
      Bs[l_k4 + 2][l_row] = v.z;
      Bs[l_k4 + 3][l_row] = v.w;
    }
    __syncthreads();
#pragma unroll
    for (int k = 0; k < BK; k++) {
      float a[TM], b[TN];
#pragma unroll
      for (int i = 0; i < TM; i++) a[i] = As[k][ty * TM + i];
#pragma unroll
      for (int j = 0; j < TN; j++) b[j] = Bs[k][tx * TN + j];
#pragma unroll
      for (int i = 0; i < TM; i++)
#pragma unroll
        for (int j = 0; j < TN; j++) acc[i][j] += a[i] * b[j];
    }
    __syncthreads();
  }
#pragma unroll
  for (int i = 0; i < TM; i++) {
    int m = m0 + ty * TM + i;
    if (m >= M) continue;
#pragma unroll
    for (int j = 0; j < TN; j++) {
      int n = n0 + tx * TN + j;
      if (n >= N) continue;
      float v = acc[i][j] + bias[n];
      if (ACT == 1) v = fmaxf(v, 0.f);
      C[(size_t)m * N + n] = v;
    }
  }
}

// ---------------------------------------------------------------------------
// padcast_tileB: fp32 weight [rs][cs] -> bf16 K-step-tiled, PRE-SWIZZLED:
//   dst granule index i = ((nblk*NT + t)*rowsPerTile + row)*4 + slot
//   holds source granule (row, gq = slot ^ ((row>>1)&3)), i.e. k in
//   [t*32 + gq*8, +8). Zero-padded outside [rs][cs].
// With this layout the GEMM's B staging is a LINEAR copy: global granule p
// -> LDS granule p (contiguous, coalesced), and the swizzled ds_read offset
// (row*4 + (kq ^ swz(row))) lands on content (row,kq). Rule #21: swizzle the
// source + the read, keep the LDS write linear.
// ---------------------------------------------------------------------------
__global__ __launch_bounds__(256) void padcast_tileB(
    const float* __restrict__ src, unsigned short* __restrict__ dst,
    int rs, int cs, int rowsPerTile, int nRowTiles, int NT) {
  const int total = nRowTiles * NT * rowsPerTile * 4;
  int i = blockIdx.x * 256 + threadIdx.x;
  if (i >= total) return;
  const int gpt = rowsPerTile * 4;  // granules per (nblk, t) tile
  int nb = i / (NT * gpt);
  int rem1 = i - nb * NT * gpt;
  int t = rem1 / gpt;
  int rem = rem1 - t * gpt;
  int row = rem >> 2;
  int slot = rem & 3;
  int gq = slot ^ ((row >> 1) & 3);
  int grow = nb * rowsPerTile + row;
  float f[8];
#pragma unroll
  for (int e = 0; e < 8; e++) {
    int k = t * 32 + gq * 8 + e;
    f[e] = (grow < rs && k < cs) ? src[(size_t)grow * cs + k] : 0.f;
  }
  uint4 o;
  o.x = pack2bf(f[0], f[1]);
  o.y = pack2bf(f[2], f[3]);
  o.z = pack2bf(f[4], f[5]);
  o.w = pack2bf(f[6], f[7]);
  *(uint4*)(dst + (size_t)i * 8) = o;
}

// ===========================================================================
// bf16 MFMA GEMM core (128x128 tile, 4 waves of 64x64, BK=32).
// Double-buffered LDS + register prefetch + raw s_barrier with
// lgkmcnt(0)-only drain. B comes from the pre-swizzled tiled layout
// ([nblk][NT][128][32]): staging is a coalesced linear copy (2 x 16B per
// thread), LDS writes linear, ds_read offsets swizzled.
// MFMA frag maps (verified): A/B lane holds row/col (lane&15), k=(lane>>4)*8+i
// C/D: col=lane&15, row=(lane>>4)*4+reg.
// ===========================================================================
template <int ACT>  // 0=none, 1=relu
__global__ __launch_bounds__(256) void mfma_gemm(
    const float* __restrict__ A, int lda, int Ka,
    const unsigned short* __restrict__ B, int NT,
    const float* __restrict__ bias, float* __restrict__ C, int Nout) {
  __shared__ unsigned short ldsA[2][128 * 32];
  __shared__ unsigned short ldsB[2][128 * 32];
  const int tid = threadIdx.x;
  const int n0 = blockIdx.x * 128;
  const int m0 = blockIdx.y * 128;

  const int arow = tid >> 1;
  const int ahalf = (tid & 1) << 4;  // k offset 0/16
  const int ag = (tid & 1) << 1;     // granule 0/2
  const int aswz = (arow >> 1) & 3;
  const int aw0 = (arow * 4 + ((ag | 0) ^ aswz)) * 8;
  const int aw1 = (arow * 4 + ((ag | 1) ^ aswz)) * 8;
  const float* aptr = A + (size_t)(m0 + arow) * lda;
  // B: tiled layout, this block's n-slice; thread covers granules tid, tid+256
  const unsigned short* bbase = B + (size_t)blockIdx.x * NT * 4096 + (size_t)tid * 8;

  const int lane = tid & 63;
  const int wave = tid >> 6;
  const int wm = (wave >> 1) << 6;
  const int wn = (wave & 1) << 6;
  const int r16 = lane & 15;
  const int kq = lane >> 4;

  int afoff[4], bfoff[4];
#pragma unroll
  for (int i = 0; i < 4; i++) {
    int rowA = wm + i * 16 + r16;
    afoff[i] = (rowA * 4 + (kq ^ ((rowA >> 1) & 3))) * 8;
    int rowB = wn + i * 16 + r16;
    bfoff[i] = (rowB * 4 + (kq ^ ((rowB >> 1) & 3))) * 8;
  }

  f32x4 acc[4][4] = {};

  float4 f[4];
  uint4 bv0, bv1;
  // ---- prologue: stage K-tile 0 into buf 0 ----
#pragma unroll
  for (int q = 0; q < 4; q++) {
    int k = ahalf + q * 4;
    f[q] = (k < Ka) ? *(const float4*)(aptr + k) : make_float4(0.f, 0.f, 0.f, 0.f);
  }
  bv0 = *(const uint4*)(bbase + 0);
  bv1 = *(const uint4*)(bbase + 2048);
  {
    uint4 w0, w1;
    w0.x = pack2bf(f[0].x, f[0].y); w0.y = pack2bf(f[0].z, f[0].w);
    w0.z = pack2bf(f[1].x, f[1].y); w0.w = pack2bf(f[1].z, f[1].w);
    w1.x = pack2bf(f[2].x, f[2].y); w1.y = pack2bf(f[2].z, f[2].w);
    w1.z = pack2bf(f[3].x, f[3].y); w1.w = pack2bf(f[3].z, f[3].w);
    *(uint4*)&ldsA[0][aw0] = w0;
    *(uint4*)&ldsA[0][aw1] = w1;
    *(uint4*)&ldsB[0][tid * 8] = bv0;
    *(uint4*)&ldsB[0][tid * 8 + 2048] = bv1;
  }

#pragma unroll 2
  for (int t = 0; t < NT; ++t) {
    const int cb = t & 1;
    asm volatile("s_waitcnt lgkmcnt(0)" ::: "memory");
    __builtin_amdgcn_s_barrier();
    if (t + 1 < NT) {
      const int k0 = (t + 1) << 5;
#pragma unroll
      for (int q = 0; q < 4; q++) {
        int k = k0 + ahalf + q * 4;
        f[q] = (k < Ka) ? *(const float4*)(aptr + k)
                        : make_float4(0.f, 0.f, 0.f, 0.f);
      }
      bv0 = *(const uint4*)(bbase + (size_t)(t + 1) * 4096);
      bv1 = *(const uint4*)(bbase + (size_t)(t + 1) * 4096 + 2048);
    }
    bf16x8 a[4], b[4];
#pragma unroll
    for (int i = 0; i < 4; i++) a[i] = *(const bf16x8*)&ldsA[cb][afoff[i]];
#pragma unroll
    for (int i = 0; i < 4; i++) b[i] = *(const bf16x8*)&ldsB[cb][bfoff[i]];
#pragma unroll
    for (int i = 0; i < 4; i++)
#pragma unroll
      for (int j = 0; j < 4; j++)
        acc[i][j] = __builtin_amdgcn_mfma_f32_16x16x32_bf16(a[i], b[j], acc[i][j], 0, 0, 0);
    if (t + 1 < NT) {
      uint4 w0, w1;
      w0.x = pack2bf(f[0].x, f[0].y); w0.y = pack2bf(f[0].z, f[0].w);
      w0.z = pack2bf(f[1].x, f[1].y); w0.w = pack2bf(f[1].z, f[1].w);
      w1.x = pack2bf(f[2].x, f[2].y); w1.y = pack2bf(f[2].z, f[2].w);
      w1.z = pack2bf(f[3].x, f[3].y); w1.w = pack2bf(f[3].z, f[3].w);
      *(uint4*)&ldsA[cb ^ 1][aw0] = w0;
      *(uint4*)&ldsA[cb ^ 1][aw1] = w1;
      *(uint4*)&ldsB[cb ^ 1][tid * 8] = bv0;
      *(uint4*)&ldsB[cb ^ 1][tid * 8 + 2048] = bv1;
    }
  }

#pragma unroll
  for (int j = 0; j < 4; j++) {
    int n = n0 + wn + j * 16 + r16;
    if (n >= Nout) continue;
    float bi = bias[n];
#pragma unroll
    for (int i = 0; i < 4; i++) {
#pragma unroll
      for (int r = 0; r < 4; r++) {
        int m = m0 + wm + i * 16 + kq * 4 + r;
        float v = acc[i][j][r] + bi;
        if (ACT == 1) v = fmaxf(v, 0.f);
        C[(size_t)m * Nout + n] = v;
      }
    }
  }
}

// ===========================================================================
// Embedding MFMA GEMM:
//  - 512 threads / block, tile 128M x 512N (FULL padded N in one block so A
//    is fetched from HBM exactly once; B is 786KB/group -> L2 resident).
//  - wave grid 2m x 4n; each wave 64x128 -> acc[4][8] f32x4.
//  - dbuf + reg-prefetch + raw-barrier pipeline.
//  - B from pre-swizzled tiled layout [g][24][512][32]: staging is a linear
//    coalesced copy (4 x 16B per thread at stride 512 granules).
//  - epilogue: groups 0-2 plain tanh stores (64-B aligned via SD=512);
//    groups 3-5 reduce the 10-row retrieval batches in LDS column chunks,
//    chunk loop FULLY UNROLLED (rule #20: runtime acc index -> scratch).
// Row space: [0,4096) txt, [4096,8192) vis, [8192,12288) usr,
// [12288,53248) rt, [53248,94208) rv, [94208,135168) ru.
// ===========================================================================
struct EmbedArgs {
  const float* A[6];
  const float* bias[6];
};

__global__ __launch_bounds__(512, 2) void embed_mfma(
    EmbedArgs ea, const unsigned short* __restrict__ Wbf,
    float* __restrict__ S, float* __restrict__ E0) {
  __shared__ unsigned short ldsA[2][128 * 32];  // 16 KB
  __shared__ unsigned short ldsB[2][512 * 32];  // 64 KB
  const int tid = threadIdx.x;
  const int m0 = blockIdx.x * 128;

  int g, base;
  if (m0 < 4096) { g = 0; base = 0; }
  else if (m0 < 8192) { g = 1; base = 4096; }
  else if (m0 < 12288) { g = 2; base = 8192; }
  else if (m0 < 53248) { g = 3; base = 12288; }
  else if (m0 < 94208) { g = 4; base = 53248; }
  else { g = 5; base = 94208; }

  // A staging: row = tid>>2 (0..127), k-granule q = tid&3 (8 fp32 -> 8 bf16)
  const int arow = tid >> 2;
  const int aq = tid & 3;
  const int aswz = (arow >> 1) & 3;
  const int awoff = (arow * 4 + (aq ^ aswz)) * 8;
  const float* aptr = ea.A[g] + (size_t)(m0 - base + arow) * FD + aq * 8;

  // B staging: linear coalesced copy of the pre-swizzled tile.
  // Thread covers granules {tid, tid+512, tid+1024, tid+1536} of the
  // 2048-granule (512 rows x 4) K-step tile.
  const unsigned short* bbase = Wbf + (size_t)g * (24 * 16384) + (size_t)tid * 8;

  const int lane = tid & 63;
  const int wave = tid >> 6;
  const int wm = (wave >> 2) << 6;  // 0 / 64
  const int wn = (wave & 3) << 7;   // 0 / 128 / 256 / 384
  const int r16 = lane & 15;
  const int kq = lane >> 4;

  int afoff[4], bfoff[8];
#pragma unroll
  for (int i = 0; i < 4; i++) {
    int rowA = wm + i * 16 + r16;
    afoff[i] = (rowA * 4 + (kq ^ ((rowA >> 1) & 3))) * 8;
  }
#pragma unroll
  for (int j = 0; j < 8; j++) {
    int rowB = wn + j * 16 + r16;
    bfoff[j] = (rowB * 4 + (kq ^ ((rowB >> 1) & 3))) * 8;
  }

  f32x4 acc[4][8] = {};

  // ---- prologue: stage K-tile 0 into buf 0 ----
  float4 fa0 = *(const float4*)(aptr + 0);
  float4 fa1 = *(const float4*)(aptr + 4);
  uint4 bv[4];
#pragma unroll
  for (int q = 0; q < 4; q++) bv[q] = *(const uint4*)(bbase + q * 4096);
  {
    uint4 aw;
    aw.x = pack2bf(fa0.x, fa0.y); aw.y = pack2bf(fa0.z, fa0.w);
    aw.z = pack2bf(fa1.x, fa1.y); aw.w = pack2bf(fa1.z, fa1.w);
    *(uint4*)&ldsA[0][awoff] = aw;
#pragma unroll
    for (int q = 0; q < 4; q++) *(uint4*)&ldsB[0][tid * 8 + q * 4096] = bv[q];
  }

  const int NT = FD / 32;  // 24
#pragma unroll 2
  for (int t = 0; t < NT; ++t) {
    const int cb = t & 1;
    asm volatile("s_waitcnt lgkmcnt(0)" ::: "memory");
    __builtin_amdgcn_s_barrier();
    if (t + 1 < NT) {
      const float* ap = aptr + (t + 1) * 32;
      fa0 = *(const float4*)(ap + 0);
      fa1 = *(const float4*)(ap + 4);
      const unsigned short* bp = bbase + (size_t)(t + 1) * 16384;
#pragma unroll
      for (int q = 0; q < 4; q++) bv[q] = *(const uint4*)(bp + q * 4096);
    }
    bf16x8 a[4], b[8];
#pragma unroll
    for (int i = 0; i < 4; i++) a[i] = *(const bf16x8*)&ldsA[cb][afoff[i]];
#pragma unroll
    for (int j = 0; j < 8; j++) b[j] = *(const bf16x8*)&ldsB[cb][bfoff[j]];
#pragma unroll
    for (int i = 0; i < 4; i++)
#pragma unroll
      for (int j = 0; j < 8; j++)
        acc[i][j] = __builtin_amdgcn_mfma_f32_16x16x32_bf16(a[i], b[j], acc[i][j], 0, 0, 0);
    if (t + 1 < NT) {
      uint4 aw;
      aw.x = pack2bf(fa0.x, fa0.y); aw.y = pack2bf(fa0.z, fa0.w);
      aw.z = pack2bf(fa1.x, fa1.y); aw.w = pack2bf(fa1.z, fa1.w);
      *(uint4*)&ldsA[cb ^ 1][awoff] = aw;
#pragma unroll
      for (int q = 0; q < 4; q++)
        *(uint4*)&ldsB[cb ^ 1][tid * 8 + q * 4096] = bv[q];
    }
  }

  const float* bias = ea.bias[g];
  if (g < 3) {
#pragma unroll
    for (int j = 0; j < 8; j++) {
      int n = wn + j * 16 + r16;
      if (n >= PD) continue;
      float bi = bias[n];
#pragma unroll
      for (int i = 0; i < 4; i++) {
#pragma unroll
        for (int r = 0; r < 4; r++) {
          int rl = m0 - base + wm + i * 16 + kq * 4 + r;
          S[((size_t)g * BS + rl) * SD + n] = tanhf(acc[i][j][r] + bi);
        }
      }
    }
    return;
  }

  // ---- g >= 3: per-batch (10-row) reduction via LDS column chunks ----
  const int R0 = m0 - base;          // multiple of 128
  const int b0 = R0 / 10;
  const int b1 = (R0 + 127) / 10;
  const int ng = b1 - b0 + 1;        // 13 or 14
  float* red = (float*)&ldsB[0][0];  // [128][68] fp32 = 34.8 KB (LDS reuse)
  const int myc = wave & 3;
  __syncthreads();  // all frag reads of last K-tile done before LDS reuse
#pragma unroll
  for (int ch = 0; ch < 8; ++ch) {   // FULLY UNROLLED: acc indices static
    if ((ch >> 1) == myc) {
      // this wave's 2 m-halves write cols [ch*64, ch*64+64) (pre-tanh + bias)
#pragma unroll
      for (int jj = 0; jj < 4; jj++) {
        int j = ((ch & 1) << 2) + jj;
        int n = wn + j * 16 + r16;
        int cl = (jj << 4) + r16;  // local col 0..63
        float bi = (n < PD) ? bias[n] : 0.f;
#pragma unroll
        for (int i = 0; i < 4; i++) {
#pragma unroll
          for (int r = 0; r < 4; r++) {
            int row = wm + i * 16 + kq * 4 + r;
            red[row * 68 + cl] = acc[i][j][r] + bi;
          }
        }
      }
    }
    __syncthreads();
    for (int task = tid; task < ng * 64; task += 512) {
      int cl = task & 63;
      int bb = b0 + (task >> 6);
      int n = (ch << 6) + cl;
      if (n < PD) {
        int rlo = bb * 10 - R0;
        int rhi = rlo + 9;
        int lo = rlo < 0 ? 0 : rlo;
        int hi = rhi > 127 ? 127 : rhi;
        float s = 0.f;
        for (int r = lo; r <= hi; r++) s += tanhf(red[r * 68 + cl]);
        size_t idx = ((size_t)g * BS + bb) * SD + n;
        if (hi - lo == 9) S[idx] = s;       // batch fully inside this tile
        else atomicAdd(&S[idx], s);         // split across two tiles
        if (g != 5 && bb == 0 && R0 == 0) {
#pragma unroll
          for (int rr = 0; rr < 10; rr++)
            E0[((size_t)(g - 3) * 10 + rr) * PD + n] = tanhf(red[rr * 68 + cl]);
        }
      }
    }
    __syncthreads();
  }
}

// ---------------------------------------------------------------------------
// Edge means (fp32): Mn[b*4+e][k]; S has padded row stride SD.
// ---------------------------------------------------------------------------
__global__ __launch_bounds__(256) void means_kernel(
    const float* __restrict__ S, float* __restrict__ Mn) {
  const int total = 4 * BS * PD;
  const size_t P = (size_t)BS * SD;
  for (int i = blockIdx.x * blockDim.x + threadIdx.x; i < total;
       i += gridDim.x * blockDim.x) {
    int m = i / PD;
    int k = i - m * PD;
    int b = m >> 2, e = m & 3;
    float v;
    const size_t o = (size_t)b * SD + k;
    if (e == 0)
      v = (S[o] + S[P + o] + S[2 * P + o]) * (1.f / 3.f);
    else if (e == 1)
      v = (S[3 * P + o] + S[o]) * (1.f / 11.f);
    else if (e == 2)
      v = (S[4 * P + o] + S[P + o]) * (1.f / 11.f);
    else
      v = (S[5 * P + o] + S[2 * P + o]) * (1.f / 11.f);
    Mn[i] = v;
  }
}

// ---------------------------------------------------------------------------
__global__ __launch_bounds__(256) void xte_kernel(
    const float* __restrict__ E0, const float* __restrict__ hg_w,
    const float* __restrict__ hg_b, float* __restrict__ XtE) {
  const int i = blockIdx.x;  // 0..19
  __shared__ float row[PD];
  for (int k = threadIdx.x; k < PD; k += 256) row[k] = E0[(size_t)i * PD + k];
  __syncthreads();
  for (int n = threadIdx.x; n < ZD; n += 256) {
    float s = 0.f;
    const float* w = hg_w + (size_t)n * PD;
    for (int k = 0; k < PD; k++) s += row[k] * w[k];
    XtE[(size_t)i * ZD + n] = s + hg_b[n];
  }
}

// ---------------------------------------------------------------------------
__global__ __launch_bounds__(256) void feat_kernel(
    const float* __restrict__ Y, const float* __restrict__ XtE,
    const float* __restrict__ sim_in, const float* __restrict__ label,
    const float* __restrict__ lbl_w, const float* __restrict__ lbl_b,
    float* __restrict__ feat) {
  const int b = blockIdx.x;
  __shared__ float w[RNUM];
  __shared__ float lbl_agg_s;
  if (threadIdx.x == 0) {
    float s[RNUM], mx = -1e30f;
    for (int r = 0; r < RNUM; r++) {
      s[r] = sim_in[(size_t)b * RNUM + r];
      mx = fmaxf(mx, s[r]);
    }
    float sum = 0.f;
    for (int r = 0; r < RNUM; r++) { s[r] = expf(s[r] - mx); sum += s[r]; }
    float la = 0.f;
    for (int r = 0; r < RNUM; r++) {
      w[r] = s[r] / sum;
      la += w[r] * label[(size_t)b * RNUM + r];
    }
    lbl_agg_s = la;
  }
  __syncthreads();
  const float* Yb = Y + (size_t)b * 4 * ZD;
  float* fb = feat + (size_t)b * 7 * ZD;
  const float la = lbl_agg_s;
  for (int n = threadIdx.x; n < ZD; n += blockDim.x) {
    float y0 = Yb[n], y1 = Yb[ZD + n], y2 = Yb[2 * ZD + n], y3 = Yb[3 * ZD + n];
    fb[n] = fmaxf(0.5f * (y0 + y1), 0.f);
    fb[ZD + n] = fmaxf(0.5f * (y0 + y2), 0.f);
    fb[2 * ZD + n] = fmaxf(0.5f * (y0 + y3), 0.f);
    float rv, rt;
    if (b == 0) {
      rv = 0.f; rt = 0.f;
      for (int r = 0; r < RNUM; r++) {
        float yp = 0.5f * (XtE[(size_t)r * ZD + n] + XtE[(size_t)(10 + r) * ZD + n]);
        rt += w[r] * fmaxf(0.5f * (y1 + yp), 0.f);
        rv += w[r] * fmaxf(0.5f * (y2 + yp), 0.f);
      }
    } else {
      rt = fmaxf(y1, 0.f);
      rv = fmaxf(y2, 0.f);
    }
    fb[3 * ZD + n] = rv;
    fb[4 * ZD + n] = rt;
    fb[5 * ZD + n] = fmaxf(y3, 0.f);
    fb[6 * ZD + n] = fmaxf(la * lbl_w[n] + lbl_b[n], 0.f);
  }
}

// ---------------------------------------------------------------------------
__global__ __launch_bounds__(256) void head_kernel(
    const float* __restrict__ h2, const float* __restrict__ p3_w,
    const float* __restrict__ p3_b, float* __restrict__ out) {
  const int wave = (blockIdx.x * blockDim.x + threadIdx.x) >> 6;
  const int lane = threadIdx.x & 63;
  if (wave >= BS) return;
  const float* row = h2 + (size_t)wave * 200;
  float s = 0.f;
  for (int k = lane; k < 200; k += 64) s += row[k] * p3_w[k];
#pragma unroll
  for (int off = 32; off; off >>= 1) s += __shfl_down(s, off, 64);
  if (lane == 0) out[wave] = 1.f / (1.f + expf(-(s + p3_b[0])));
}

// ---------------------------------------------------------------------------
extern "C" void kernel_launch(void* const* d_in, const int* in_sizes, int n_in,
                              void* d_out, int out_size, void* d_ws,
                              size_t ws_size, hipStream_t stream) {
  (void)in_sizes; (void)n_in; (void)out_size; (void)ws_size;

  const float* visual = (const float*)d_in[0];
  const float* textual = (const float*)d_in[1];
  const float* similarity = (const float*)d_in[2];
  const float* r_visual = (const float*)d_in[3];
  const float* r_textual = (const float*)d_in[4];
  const float* r_label = (const float*)d_in[5];
  const float* user = (const float*)d_in[6];
  const float* r_user = (const float*)d_in[7];
  const float* vis_w = (const float*)d_in[9];
  const float* vis_b = (const float*)d_in[10];
  const float* txt_w = (const float*)d_in[11];
  const float* txt_b = (const float*)d_in[12];
  const float* usr_w = (const float*)d_in[13];
  const float* usr_b = (const float*)d_in[14];
  const float* rvis_w = (const float*)d_in[15];
  const float* rvis_b = (const float*)d_in[16];
  const float* rtxt_w = (const float*)d_in[17];
  const float* rtxt_b = (const float*)d_in[18];
  const float* rusr_w = (const float*)d_in[19];
  const float* rusr_b = (const float*)d_in[20];
  const float* hg_w = (const float*)d_in[21];
  const float* hg_b = (const float*)d_in[22];
  const float* lbl_w = (const float*)d_in[23];
  const float* lbl_b = (const float*)d_in[24];
  const float* p1_w = (const float*)d_in[25];
  const float* p1_b = (const float*)d_in[26];
  const float* p2_w = (const float*)d_in[27];
  const float* p2_b = (const float*)d_in[28];
  const float* p3_w = (const float*)d_in[29];
  const float* p3_b = (const float*)d_in[30];
  float* out = (float*)d_out;

  // workspace layout
  float* ws = (float*)d_ws;
  float* S = ws;                            // 6*4096*512 (padded stride)
  float* E0 = S + (size_t)6 * BS * SD;      // 20*500
  float* XtE = E0 + 20 * PD;                // 20*300
  float* Mn = XtE + 20 * ZD;                // 16384*500
  float* Y = Mn + (size_t)4 * BS * PD;      // 16384*300
  float* feat = Y + (size_t)4 * BS * ZD;    // 4096*2100
  float* h1 = feat + (size_t)BS * 7 * ZD;   // 4096*800
  float* h2 = h1 + (size_t)BS * 800;        // 4096*200
  unsigned short* Wbf = (unsigned short*)(h2 + (size_t)BS * 200);  // 6*24*512*32
  unsigned short* hgwbf = Wbf + (size_t)6 * 24 * 16384;            // 3*16*128*32
  unsigned short* p1wbf = hgwbf + (size_t)3 * 16 * 4096;           // 7*66*128*32

  // pre-cast weights to pre-swizzled K-step-tiled bf16
  const float* ew[6] = {txt_w, vis_w, usr_w, rtxt_w, rvis_w, rusr_w};
  for (int g = 0; g < 6; g++) {
    // [1 tile of 512 rows][NT=24]
    padcast_tileB<<<(24 * 512 * 4 + 255) / 256, 256, 0, stream>>>(
        ew[g], Wbf + (size_t)g * 24 * 16384, PD, FD, 512, 1, 24);
  }
  // Y-layer B: rows=ZD(300)->3x128, K=PD(500)->Kp=512, NT=16
  padcast_tileB<<<(3 * 16 * 128 * 4 + 255) / 256, 256, 0, stream>>>(
      hg_w, hgwbf, ZD, PD, 128, 3, 16);
  // p1 B: rows=800->7x128, K=2100->Kp=2112, NT=66
  padcast_tileB<<<(7 * 66 * 128 * 4 + 255) / 256, 256, 0, stream>>>(
      p1_w, p1wbf, 800, 2100, 128, 7, 66);

  // zero only the atomically-accumulated retrieval-group region of S
  hipMemsetAsync(S + (size_t)3 * BS * SD, 0, (size_t)3 * BS * SD * sizeof(float),
                 stream);

  EmbedArgs ea;
  ea.A[0] = textual;  ea.bias[0] = txt_b;
  ea.A[1] = visual;   ea.bias[1] = vis_b;
  ea.A[2] = user;     ea.bias[2] = usr_b;
  ea.A[3] = r_textual; ea.bias[3] = rtxt_b;
  ea.A[4] = r_visual;  ea.bias[4] = rvis_b;
  ea.A[5] = r_user;    ea.bias[5] = rusr_b;

  // one block per 128-row M-tile, full N=512 per block (A fetched once)
  embed_mfma<<<dim3(135168 / 128), 512, 0, stream>>>(ea, Wbf, S, E0);
  xte_kernel<<<20, 256, 0, stream>>>(E0, hg_w, hg_b, XtE);
  means_kernel<<<4096, 256, 0, stream>>>(S, Mn);
  mfma_gemm<0><<<dim3(3, 16384 / 128), 256, 0, stream>>>(
      Mn, PD, PD, hgwbf, 16, hg_b, Y, ZD);
  feat_kernel<<<BS, 256, 0, stream>>>(Y, XtE, similarity, r_label, lbl_w, lbl_b,
                                      feat);
  mfma_gemm<1><<<dim3(7, BS / 128), 256, 0, stream>>>(
      feat, 2100, 2100, p1wbf, 66, p1_b, h1, 800);
  gemm_kernel<1><<<dim3(BS / BM, (200 + BN - 1) / BN), 256, 0, stream>>>(
      h1, p2_w, p2_b, h2, BS, 200, 800);
  head_kernel<<<BS * 64 / 256, 256, 0, stream>>>(h2, p3_w, p3_b, out);
}